// Round 6
// baseline (408.558 us; speedup 1.0000x reference)
//
#include <hip/hip_runtime.h>
#include <math.h>

// ----------------------------------------------------------------------------
// MultiHeadAttentionQuantum: 8-qubit RX/CNOT-ring circuit projections + MHA.
//
// Timing model (validated rounds 2-5): dur_us = harness fill (~175us, fixed)
//   + qproj3 + attn (~78) + qproj1.
//
// Round-8 (this round): 8-lanes-per-sample qsim relayout. Insight: v_pk_fma
//   is NOT double-throughput on gfx950 (FP32 peak 157.3TF = scalar rate), so
//   round-7's packing only helped via code size. The real limiter is 2
//   waves/SIMD occupancy (state = 128 VGPR) + ~30KB unrolled body at the I$
//   edge. New layout: d = (lane&7)<<5 | loc5, 32 amps/lane (64 VGPR state),
//   peak live ~110 -> __launch_bounds__(256,4), 4-5 waves/SIMD, ~half the
//   per-wave code. Lane bits (b2,b1,b0) = data bits (d7,d6,d5) = wires
//   (0,1,2); loc bit k = wire 7-k.
//   Gate masks (re-derived from the verified 4-lane algebra):
//     L1: 0x80=lane-xor4 (2-DPP), 0x40=xor2, 0x20=xor1, 0x10..0x01 local.
//     L2: 0xC0=xor6 (2-DPP), 0x60=xor3, 0x30=xor1+loc0x10, 0x18,0C,06,03
//         local, 0xC1=xor6+loc0x01.
//   xor4 = RHM o QX3; xor6 = RHM o QX1 (chained DPP movs, VALU pipe).
//   Readout masks r_i={D5,BF,5F,AF,57,AB,55,AA} -> (rh3=r>>5, rl5=r&0x1F):
//     pruned 4-group WHT over loc (uhi,ulo): A(2,5) B(3,7) C(1,7) D(2,7)
//     E(1,3) F(1,2); then signed 3-stage lane-WHT (xor1,xor2,xor4);
//     lane 6 writes o0(A); lane 2 writes o2(B),o4(D),o6(A); lane 5 writes
//     o1(B),o3(C),o5(E),o7(F).
//
// attn (verified round 3, ~78us): lane owns j = t*256 + lane*4 + c so each
//   attn-row store is one dense aligned 1 KB block; 8 rows/wave, grid 2048.
// ----------------------------------------------------------------------------

#define NSAMP 32768  // B*S = 32*1024

// DPP ctrl codes (gfx9/CDNA): quad_perm xor1/2/3, row mirrors.
#define QX1 0xB1  // [1,0,3,2]
#define QX2 0x4E  // [2,3,0,1]
#define QX3 0x1B  // [3,2,1,0]
#define ROW_MIRROR 0x140       // lane ^ 15 within 16
#define ROW_HALF_MIRROR 0x141  // lane ^ 7 within 8

template <int CTRL>
__device__ __forceinline__ float dppf(float x) {
  int xi = __float_as_int(x);
  return __int_as_float(
      __builtin_amdgcn_update_dpp(xi, xi, CTRL, 0xF, 0xF, false));
}

// Chained DPP: value from lane ^ (7 ^ xor(P1)). P1=QX3 -> xor4; QX1 -> xor6.
template <int P1>
__device__ __forceinline__ float dpp2x(float x) {
  return dppf<ROW_HALF_MIRROR>(dppf<P1>(x));
}

// ---- gates on vr/vi[32] (local bits 0..4), 8 lanes/sample -----------------

// Cross-lane RX via single DPP (lane-xor 1,2,3).
template <int CTRL>
__device__ __forceinline__ void cg1(float c, float s, float* vr, float* vi) {
#pragma unroll
  for (int m = 0; m < 32; ++m) {
    const float pr = dppf<CTRL>(vr[m]);
    const float pi = dppf<CTRL>(vi[m]);
    vr[m] = fmaf(c, vr[m], s * pi);
    vi[m] = fmaf(c, vi[m], -s * pr);
  }
}

// Cross-lane RX via chained DPP (lane-xor 4 or 6).
template <int P1>
__device__ __forceinline__ void cg2(float c, float s, float* vr, float* vi) {
#pragma unroll
  for (int m = 0; m < 32; ++m) {
    const float pr = dpp2x<P1>(vr[m]);
    const float pi = dpp2x<P1>(vi[m]);
    vr[m] = fmaf(c, vr[m], s * pi);
    vi[m] = fmaf(c, vi[m], -s * pr);
  }
}

// Cross-lane (1- or 2-DPP) + local-mask RX.
template <int P1, bool TWO, int ML>
__device__ __forceinline__ void cgl(float c, float s, float* vr, float* vi) {
  constexpr int HB = ML >= 16 ? 16 : ML >= 8 ? 8 : ML >= 4 ? 4
                     : ML >= 2 ? 2 : 1;
#pragma unroll
  for (int m = 0; m < 32; ++m) {
    if (!(m & HB)) {
      const int p = m ^ ML;
      float prl, pil, prp, pip;
      if constexpr (TWO) {
        prl = dpp2x<P1>(vr[p]); pil = dpp2x<P1>(vi[p]);
        prp = dpp2x<P1>(vr[m]); pip = dpp2x<P1>(vi[m]);
      } else {
        prl = dppf<P1>(vr[p]); pil = dppf<P1>(vi[p]);
        prp = dppf<P1>(vr[m]); pip = dppf<P1>(vi[m]);
      }
      vr[m] = fmaf(c, vr[m], s * pil);
      vi[m] = fmaf(c, vi[m], -s * prl);
      vr[p] = fmaf(c, vr[p], s * pip);
      vi[p] = fmaf(c, vi[p], -s * prp);
    }
  }
}

// Intra-lane RX along local mask ML.
template <int ML>
__device__ __forceinline__ void gl(float c, float s, float* vr, float* vi) {
  constexpr int HB = ML >= 16 ? 16 : ML >= 8 ? 8 : ML >= 4 ? 4
                     : ML >= 2 ? 2 : 1;
#pragma unroll
  for (int m = 0; m < 32; ++m) {
    if (!(m & HB)) {
      const int p = m ^ ML;
      float a0r = vr[m], a0i = vi[m], a1r = vr[p], a1i = vi[p];
      vr[m] = fmaf(c, a0r, s * a1i);
      vi[m] = fmaf(c, a0i, -s * a1r);
      vr[p] = fmaf(c, a1r, s * a0i);
      vi[p] = fmaf(c, a1i, -s * a0r);
    }
  }
}

// 3-stage signed lane WHT within 8-lane groups: lane u gets
// sum_{l'} (-1)^<u,l'> x[l'].
__device__ __forceinline__ float lane_wht8(float v, int l3) {
  float u = dppf<QX1>(v);
  v = (l3 & 1) ? (u - v) : (v + u);
  u = dppf<QX2>(v);
  v = (l3 & 2) ? (u - v) : (v + u);
  u = dpp2x<QX3>(v);  // value from lane^4
  v = (l3 & 4) ? (u - v) : (v + u);
  return v;
}

// in: sample angle rows [samp][8]; wc/wsn: cos/sin of 16 weight half-angles
// (LDS); out: [samp][8] expvals. Wave handles samples [sampBase, sampBase+8).
__device__ __forceinline__ void qsim_wave(const float* __restrict__ in,
                                          float* __restrict__ outp,
                                          int sampBase,
                                          const float* __restrict__ wc,
                                          const float* __restrict__ wsn) {
  const int lane = threadIdx.x & 63;
  const int l3 = lane & 7;
  const int samp = sampBase + (lane >> 3);

  // Input trig: each lane computes all 8 wires of its sample.
  const float* row = in + (size_t)samp * 8;
  float ci[8], si[8];
#pragma unroll
  for (int w = 0; w < 8; ++w) {
    const float half = 0.5f * row[w];
    ci[w] = cosf(half);
    si[w] = sinf(half);
  }

  // Product-state magnitudes: lane bits (b2,b1,b0) = wires (0,1,2);
  // loc bit k = wire 7-k (doubling k=0..4).
  float mm[32];
  mm[0] = ((l3 & 4) ? si[0] : ci[0]) * ((l3 & 2) ? si[1] : ci[1]) *
          ((l3 & 1) ? si[2] : ci[2]);
#pragma unroll
  for (int k = 0; k < 5; ++k) {
    const float cc = ci[7 - k], ss = si[7 - k];
#pragma unroll
    for (int t = (1 << k) - 1; t >= 0; --t) {
      mm[t + (1 << k)] = mm[t] * ss;
      mm[t] = mm[t] * cc;
    }
  }

  // Phase (-i)^popc(d): local part compile-time, lane part runtime (0..3).
  float vr[32], vi[32];
  const int pq = __builtin_popcount(l3) & 3;
#pragma unroll
  for (int m = 0; m < 32; ++m) {
    const int pl = __builtin_popcount(m) & 3;
    const float t = mm[m];
    if (pl == 0) { vr[m] = t;    vi[m] = 0.0f; }
    else if (pl == 1) { vr[m] = 0.0f; vi[m] = -t; }
    else if (pl == 2) { vr[m] = -t;   vi[m] = 0.0f; }
    else { vr[m] = 0.0f; vi[m] = t; }
  }
  if (pq == 1) {  // * (-i)
#pragma unroll
    for (int m = 0; m < 32; ++m) {
      const float t = vr[m];
      vr[m] = vi[m];
      vi[m] = -t;
    }
  } else if (pq == 2) {  // * (-1)
#pragma unroll
    for (int m = 0; m < 32; ++m) {
      vr[m] = -vr[m];
      vi[m] = -vi[m];
    }
  } else if (pq == 3) {  // * (i)
#pragma unroll
    for (int m = 0; m < 32; ++m) {
      const float t = vr[m];
      vr[m] = -vi[m];
      vi[m] = t;
    }
  }

  // Layer 1 RX (weight idx 0..7 = wires 0..7), masks e_{7-w}.
  cg2<QX3>(wc[0], wsn[0], vr, vi);  // 0x80: lane-xor4
  cg1<QX2>(wc[1], wsn[1], vr, vi);  // 0x40: lane-xor2
  cg1<QX1>(wc[2], wsn[2], vr, vi);  // 0x20: lane-xor1
  gl<0x10>(wc[3], wsn[3], vr, vi);
  gl<0x08>(wc[4], wsn[4], vr, vi);
  gl<0x04>(wc[5], wsn[5], vr, vi);
  gl<0x02>(wc[6], wsn[6], vr, vi);
  gl<0x01>(wc[7], wsn[7], vr, vi);
  // Layer 2 RX (idx 8..15), masks {C0,60,30,18,0C,06,03,C1} (verified set).
  cg2<QX1>(wc[8], wsn[8], vr, vi);                 // 0xC0: lane-xor6
  cg1<QX3>(wc[9], wsn[9], vr, vi);                 // 0x60: lane-xor3
  cgl<QX1, false, 0x10>(wc[10], wsn[10], vr, vi);  // 0x30: xor1 + loc 0x10
  gl<0x18>(wc[11], wsn[11], vr, vi);
  gl<0x0C>(wc[12], wsn[12], vr, vi);
  gl<0x06>(wc[13], wsn[13], vr, vi);
  gl<0x03>(wc[14], wsn[14], vr, vi);
  cgl<QX1, true, 0x01>(wc[15], wsn[15], vr, vi);   // 0xC1: xor6 + loc 0x01

  // Pruned readout. Masks (rh3, uhi, ulo): i0(6;2,5) i1(5;3,7) i2(2;3,7)
  // i3(5;1,7) i4(2;2,7) i5(5;1,3) i6(2;2,5) i7(5;1,2).
  // Per group g = loc>>3: |amp|^2, 3-stage WHT over loc bits 0..2, then
  // signed accumulation with (-1)^popc(uhi&g).
  float accA, accB, accC, accD, accE, accF;
#pragma unroll
  for (int g = 0; g < 4; ++g) {
    float w[8];
#pragma unroll
    for (int j = 0; j < 8; ++j) {
      const int m = g * 8 + j;
      w[j] = fmaf(vr[m], vr[m], vi[m] * vi[m]);
    }
#pragma unroll
    for (int k = 0; k < 3; ++k) {
#pragma unroll
      for (int j = 0; j < 8; ++j) {
        if (!(j & (1 << k))) {
          const int j2 = j | (1 << k);
          const float a = w[j], b = w[j2];
          w[j] = a + b;
          w[j2] = a - b;
        }
      }
    }
    // A:(uhi2) + + - -, B:(uhi3) + - - +, C/E/F:(uhi1) + - + -, D:(uhi2).
    if (g == 0) {
      accA = w[5]; accB = w[7]; accC = w[7]; accD = w[7];
      accE = w[3]; accF = w[2];
    } else if (g == 1) {
      accA += w[5]; accB -= w[7]; accC -= w[7]; accD += w[7];
      accE -= w[3]; accF -= w[2];
    } else if (g == 2) {
      accA -= w[5]; accB -= w[7]; accC += w[7]; accD -= w[7];
      accE += w[3]; accF += w[2];
    } else {
      accA -= w[5]; accB += w[7]; accC -= w[7]; accD -= w[7];
      accE -= w[3]; accF -= w[2];
    }
  }

  // Signed lane-WHT over lane bits (xor1, xor2, xor4); read at u = rh3.
  const float oA = lane_wht8(accA, l3);
  const float oB = lane_wht8(accB, l3);
  const float oC = lane_wht8(accC, l3);
  const float oD = lane_wht8(accD, l3);
  const float oE = lane_wht8(accE, l3);
  const float oF = lane_wht8(accF, l3);

  float* orow = outp + (size_t)samp * 8;
  if (l3 == 6) orow[0] = oA;
  if (l3 == 2) {
    orow[2] = oB;
    orow[4] = oD;
    orow[6] = oA;
  }
  if (l3 == 5) {
    orow[1] = oB;
    orow[3] = oC;
    orow[5] = oE;
    orow[7] = oF;
  }
}

// Per-block weight trig into LDS (threads 0..31), then qsim per wave.
__device__ __forceinline__ void weight_trig(const float* __restrict__ w,
                                            float* __restrict__ tc,
                                            float* __restrict__ tsn) {
  if (threadIdx.x < 32) {
    const int a = threadIdx.x & 15;
    const float half = 0.5f * w[a];
    if (threadIdx.x < 16)
      tc[a] = cosf(half);
    else
      tsn[a] = sinf(half);
  }
  __syncthreads();
}

__global__ __launch_bounds__(256, 4) void mhaq_qproj3_kernel(
    const float* __restrict__ q, const float* __restrict__ k,
    const float* __restrict__ v, const float* __restrict__ wq,
    const float* __restrict__ wk, const float* __restrict__ wv,
    float* __restrict__ qp, float* __restrict__ kp, float* __restrict__ vp) {
  __shared__ float tc[16], tsn[16];
  const int wg = blockIdx.x * 4 + (threadIdx.x >> 6);  // 0..12287
  const int proj = wg >> 12;  // 4096 waves per projection; block-uniform
  const float* wsel = proj == 0 ? wq : proj == 1 ? wk : wv;
  weight_trig(wsel, tc, tsn);
  const float* in = proj == 0 ? q : proj == 1 ? k : v;
  float* op = proj == 0 ? qp : proj == 1 ? kp : vp;
  qsim_wave(in, op, (wg & 4095) * 8, tc, tsn);
}

__global__ __launch_bounds__(256, 4) void mhaq_qproj1_kernel(
    const float* __restrict__ ctx, const float* __restrict__ wd,
    float* __restrict__ outp) {
  __shared__ float tc[16], tsn[16];
  weight_trig(wd, tc, tsn);
  const int wg = blockIdx.x * 4 + (threadIdx.x >> 6);  // 0..4095
  qsim_wave(ctx, outp, wg * 8, tc, tsn);
}

// Full-wave reductions: quad DPP + row mirrors + 2 shfl stages (only DS use).
__device__ __forceinline__ float wred_sum(float v) {
  v += dppf<QX1>(v);
  v += dppf<QX2>(v);
  v += dppf<ROW_HALF_MIRROR>(v);  // xor7 == xor4 after quad-uniform
  v += dppf<ROW_MIRROR>(v);       // xor15 == xor8 after 8-uniform
  v += __shfl_xor(v, 16, 64);
  v += __shfl_xor(v, 32, 64);
  return v;
}
__device__ __forceinline__ float wred_max(float v) {
  v = fmaxf(v, dppf<QX1>(v));
  v = fmaxf(v, dppf<QX2>(v));
  v = fmaxf(v, dppf<ROW_HALF_MIRROR>(v));
  v = fmaxf(v, dppf<ROW_MIRROR>(v));
  v = fmaxf(v, __shfl_xor(v, 16, 64));
  v = fmaxf(v, __shfl_xor(v, 32, 64));
  return v;
}

// Attention: one wave per (b,h, 8-row chunk); K/V head slice in VGPRs.
// Lane owns j = t*256 + lane*4 + c (t,c in 0..3) so the attn-row store for
// each t is one dense, aligned 1 KB block per wave instruction (full-line
// HBM writes). Reductions/PV are ownership-agnostic.
__global__ __launch_bounds__(256, 2) void mhaq_attn_kernel(
    const float* __restrict__ qp, const float* __restrict__ kp,
    const float* __restrict__ vp, float* __restrict__ ctx,
    float* __restrict__ attn) {
  const int wg = blockIdx.x * 4 + (threadIdx.x >> 6);  // 0..8191
  const int bh = wg >> 7;      // 64 (b,h) pairs, 128 chunks each
  const int chunk = wg & 127;  // 8 rows per chunk
  const int b = bh >> 1, h = bh & 1;
  const int lane = threadIdx.x & 63;

  float4 kreg[16], vreg[16];
  const float* kbase = kp + (size_t)b * 1024 * 8 + h * 4;
  const float* vbase = vp + (size_t)b * 1024 * 8 + h * 4;
#pragma unroll
  for (int t = 0; t < 4; ++t) {
#pragma unroll
    for (int c = 0; c < 4; ++c) {
      const size_t j = (size_t)t * 256 + lane * 4 + c;
      kreg[t * 4 + c] = *(const float4*)(kbase + j * 8);
      vreg[t * 4 + c] = *(const float4*)(vbase + j * 8);
    }
  }

  for (int r = 0; r < 8; ++r) {
    const int i = chunk * 8 + r;
    const float4 qv = *(const float4*)(qp + ((size_t)b * 1024 + i) * 8 + h * 4);
    float e[16];
    float mx = -1e30f;
#pragma unroll
    for (int t = 0; t < 16; ++t) {
      float s = qv.x * kreg[t].x + qv.y * kreg[t].y + qv.z * kreg[t].z +
                qv.w * kreg[t].w;
      s *= 0.5f;  // 1/sqrt(D), D=4
      e[t] = s;
      mx = fmaxf(mx, s);
    }
    mx = wred_max(mx);
    float sum = 0.0f;
#pragma unroll
    for (int t = 0; t < 16; ++t) {
      e[t] = __expf(e[t] - mx);
      sum += e[t];
    }
    sum = wred_sum(sum);
    const float rinv = 1.0f / sum;

    float a0 = 0.f, a1 = 0.f, a2 = 0.f, a3 = 0.f;
    float* arow = attn + ((size_t)(bh * 1024 + i)) * 1024;
#pragma unroll
    for (int t = 0; t < 4; ++t) {
      float p0 = e[4 * t] * rinv, p1 = e[4 * t + 1] * rinv,
            p2 = e[4 * t + 2] * rinv, p3 = e[4 * t + 3] * rinv;
      // Dense store: 64 lanes x float4 = contiguous 1 KB at arow + t*1024B.
      *(float4*)(arow + t * 256 + lane * 4) = make_float4(p0, p1, p2, p3);
      a0 = fmaf(p0, vreg[4 * t].x, a0);
      a1 = fmaf(p0, vreg[4 * t].y, a1);
      a2 = fmaf(p0, vreg[4 * t].z, a2);
      a3 = fmaf(p0, vreg[4 * t].w, a3);
      a0 = fmaf(p1, vreg[4 * t + 1].x, a0);
      a1 = fmaf(p1, vreg[4 * t + 1].y, a1);
      a2 = fmaf(p1, vreg[4 * t + 1].z, a2);
      a3 = fmaf(p1, vreg[4 * t + 1].w, a3);
      a0 = fmaf(p2, vreg[4 * t + 2].x, a0);
      a1 = fmaf(p2, vreg[4 * t + 2].y, a1);
      a2 = fmaf(p2, vreg[4 * t + 2].z, a2);
      a3 = fmaf(p2, vreg[4 * t + 2].w, a3);
      a0 = fmaf(p3, vreg[4 * t + 3].x, a0);
      a1 = fmaf(p3, vreg[4 * t + 3].y, a1);
      a2 = fmaf(p3, vreg[4 * t + 3].z, a2);
      a3 = fmaf(p3, vreg[4 * t + 3].w, a3);
    }
    a0 = wred_sum(a0);
    a1 = wred_sum(a1);
    a2 = wred_sum(a2);
    a3 = wred_sum(a3);
    if (lane == 0)
      *(float4*)(ctx + ((size_t)b * 1024 + i) * 8 + h * 4) =
          make_float4(a0, a1, a2, a3);
  }
}

extern "C" void kernel_launch(void* const* d_in, const int* in_sizes, int n_in,
                              void* d_out, int out_size, void* d_ws,
                              size_t ws_size, hipStream_t stream) {
  (void)in_sizes; (void)n_in; (void)out_size; (void)ws_size;
  const float* q = (const float*)d_in[0];
  const float* k = (const float*)d_in[1];
  const float* v = (const float*)d_in[2];
  const float* wq = (const float*)d_in[3];
  const float* wk = (const float*)d_in[4];
  const float* wv = (const float*)d_in[5];
  const float* wd = (const float*)d_in[6];
  float* outp = (float*)d_out;  // [0, 262144): out; then attn (B,H,S,S)
  float* attn = outp + 262144;

  float* wsf = (float*)d_ws;
  float* qp = wsf;
  float* kp = qp + (size_t)NSAMP * 8;
  float* vp = kp + (size_t)NSAMP * 8;
  float* ctx = vp + (size_t)NSAMP * 8;  // concat layout [b,s,h*4+d]

  hipLaunchKernelGGL(mhaq_qproj3_kernel, dim3(3072), dim3(256), 0, stream, q,
                     k, v, wq, wk, wv, qp, kp, vp);
  hipLaunchKernelGGL(mhaq_attn_kernel, dim3(2048), dim3(256), 0, stream, qp,
                     kp, vp, ctx, attn);
  hipLaunchKernelGGL(mhaq_qproj1_kernel, dim3(1024), dim3(256), 0, stream,
                     ctx, wd, outp);
}

// Round 7
// 339.714 us; speedup vs baseline: 1.2027x; 1.2027x over previous
//
#include <hip/hip_runtime.h>
#include <math.h>

// ----------------------------------------------------------------------------
// MultiHeadAttentionQuantum: 8-qubit RX/CNOT-ring circuit projections + MHA.
//
// Timing model (validated rounds 2-6): dur_us = harness fill (~172us, fixed)
//   + qproj3 + attn (~78) + qproj1.
//
// Round-9 (this round): revert to the round-5 packed 4-lane qsim (best
//   measured, 364.7us total; round-6's 8-lane relayout regressed +44us from
//   8x redundant per-lane trig) and fold layer-1 RX into the product state:
//   reference circuit applies RX(x_w) [embedding] immediately followed by
//   RX(th0_w) [entangler layer 1] on the same wire with no CNOT between;
//   RX(a)RX(b) = RX(a+b), so the initial product state is built with
//   half-angle 0.5*x_w + 0.5*th0_w and ALL 8 layer-1 gates vanish. The
//   (-i)^popc(d) phase structure and everything after the first CNOT ring
//   (L2 masks, readout) are unchanged. Halves qsim gate work exactly.
//
// qsim (round-5, verified): amps packed as 32 f2 along local bit5 (wire 2):
//   vr[m] = (amp m, amp m+32). L2 gates: 0xC0 gq0<QX3>, 0x60 gq_l20<QX1>,
//   0x30 gl30, 0x18/0C/06/03 gl, 0xC1 gq_l1<QX3>. Pruned WHT readout.
//
// attn (verified round 3, ~78us): lane owns j = t*256 + lane*4 + c so each
//   attn-row store is one dense aligned 1 KB block; 8 rows/wave, grid 2048.
// ----------------------------------------------------------------------------

#define NSAMP 32768  // B*S = 32*1024

typedef float f2 __attribute__((ext_vector_type(2)));

// DPP ctrl codes (gfx9/CDNA): quad_perm xor1/2/3, quad bcast j, row mirrors.
#define QX1 0xB1  // [1,0,3,2]
#define QX2 0x4E  // [2,3,0,1]
#define QX3 0x1B  // [3,2,1,0]
#define QB0 0x00
#define QB1 0x55
#define QB2 0xAA
#define QB3 0xFF
#define ROW_MIRROR 0x140       // lane ^ 15 within 16
#define ROW_HALF_MIRROR 0x141  // lane ^ 7 within 8

template <int CTRL>
__device__ __forceinline__ float dppf(float x) {
  int xi = __float_as_int(x);
  return __int_as_float(
      __builtin_amdgcn_update_dpp(xi, xi, CTRL, 0xF, 0xF, false));
}

template <int CTRL>
__device__ __forceinline__ f2 dpp2(f2 v) {
  f2 r;
  r.x = dppf<CTRL>(v.x);
  r.y = dppf<CTRL>(v.y);
  return r;
}

__device__ __forceinline__ f2 swap2(f2 v) {
  f2 r;
  r.x = v.y;
  r.y = v.x;
  return r;
}

#define F2FMA(a, b, c) __builtin_elementwise_fma((a), (b), (c))

// ---- packed gates: vr/vi are 32 x f2; halves = local bit5 (0 / 1) ----------

// Cross-lane RX, no local mask (0xC0).
template <int CTRL>
__device__ __forceinline__ void gq0(float c, float s, f2* vr, f2* vi) {
  const f2 c2 = {c, c}, s2 = {s, s};
#pragma unroll
  for (int m = 0; m < 32; ++m) {
    f2 pr = dpp2<CTRL>(vr[m]);
    f2 pi = dpp2<CTRL>(vi[m]);
    vr[m] = F2FMA(c2, vr[m], s2 * pi);
    vi[m] = F2FMA(c2, vi[m], -s2 * pr);
  }
}

// Cross-lane RX + local bit0 (0xC1).
template <int CTRL>
__device__ __forceinline__ void gq_l1(float c, float s, f2* vr, f2* vi) {
  const f2 c2 = {c, c}, s2 = {s, s};
#pragma unroll
  for (int m = 0; m < 32; m += 2) {
    f2 pr0 = dpp2<CTRL>(vr[m]), pi0 = dpp2<CTRL>(vi[m]);
    f2 pr1 = dpp2<CTRL>(vr[m + 1]), pi1 = dpp2<CTRL>(vi[m + 1]);
    vr[m] = F2FMA(c2, vr[m], s2 * pi1);
    vi[m] = F2FMA(c2, vi[m], -s2 * pr1);
    vr[m + 1] = F2FMA(c2, vr[m + 1], s2 * pi0);
    vi[m + 1] = F2FMA(c2, vi[m + 1], -s2 * pr0);
  }
}

// Cross-lane RX + local bit5 (0x60): partner is DPP of the other half.
template <int CTRL>
__device__ __forceinline__ void gq_l20(float c, float s, f2* vr, f2* vi) {
  const f2 c2 = {c, c}, s2 = {s, s};
#pragma unroll
  for (int m = 0; m < 32; ++m) {
    f2 pr = dpp2<CTRL>(vr[m]);
    f2 pi = dpp2<CTRL>(vi[m]);
    vr[m] = F2FMA(c2, vr[m], s2 * swap2(pi));
    vi[m] = F2FMA(c2, vi[m], -s2 * swap2(pr));
  }
}

// Intra-lane RX, mask within bits0..4 (both halves identical pattern).
template <int ML>
__device__ __forceinline__ void gl(float c, float s, f2* vr, f2* vi) {
  constexpr int HB = ML >= 16 ? 16 : ML >= 8 ? 8 : ML >= 4 ? 4
                     : ML >= 2 ? 2 : 1;
  const f2 c2 = {c, c}, s2 = {s, s};
#pragma unroll
  for (int m = 0; m < 32; ++m) {
    if (!(m & HB)) {
      const int p = m ^ ML;
      f2 a0r = vr[m], a0i = vi[m], a1r = vr[p], a1i = vi[p];
      vr[m] = F2FMA(c2, a0r, s2 * a1i);
      vi[m] = F2FMA(c2, a0i, -s2 * a1r);
      vr[p] = F2FMA(c2, a1r, s2 * a0i);
      vi[p] = F2FMA(c2, a1i, -s2 * a0r);
    }
  }
}

// Intra-lane RX, mask = bits4+5 (0x30): partner = other half of m^0x10.
__device__ __forceinline__ void gl30(float c, float s, f2* vr, f2* vi) {
  const f2 c2 = {c, c}, s2 = {s, s};
#pragma unroll
  for (int m = 0; m < 32; ++m) {
    if (!(m & 0x10)) {
      const int p = m ^ 0x10;
      f2 or0 = vr[m], oi0 = vi[m], or1 = vr[p], oi1 = vi[p];
      vr[m] = F2FMA(c2, or0, s2 * swap2(oi1));
      vi[m] = F2FMA(c2, oi0, -s2 * swap2(or1));
      vr[p] = F2FMA(c2, or1, s2 * swap2(oi0));
      vi[p] = F2FMA(c2, oi1, -s2 * swap2(or0));
    }
  }
}

// 2-stage signed quad WHT: returns, in quad-lane u, sum_q (-1)^<u,q> W_q.
__device__ __forceinline__ float quad_wht(float v, int qq) {
  float u = dppf<QX1>(v);
  v = (qq & 1) ? (u - v) : (v + u);
  u = dppf<QX2>(v);
  v = (qq & 2) ? (u - v) : (v + u);
  return v;
}

// in:  sample angle rows [samp][8]; wc/wsn: cos/sin of the 8 layer-2 weight
// half-angles (LDS, idx 8..15); thw: 0.5*theta0_w (layer-1 fold, idx 0..7);
// out: [samp][8] expvals. Wave handles samples [sampBase, sampBase+16).
__device__ __forceinline__ void qsim_wave(const float* __restrict__ in,
                                          float* __restrict__ outp,
                                          int sampBase,
                                          const float* __restrict__ wc,
                                          const float* __restrict__ wsn,
                                          const float* __restrict__ thw) {
  const int lane = threadIdx.x & 63;
  const int qq = lane & 3;
  const int g = lane >> 2;
  const int samp = sampBase + g;

  // Input trig with layer-1 RX folded in: RX(x)RX(th0) = RX(x+th0), so the
  // product state uses half-angle 0.5*x_w + 0.5*th0_w. Lane qq computes
  // wires 2qq, 2qq+1; quad-broadcast all 8.
  const float2 xx = *(const float2*)(in + (size_t)samp * 8 + 2 * qq);
  float h0 = 0.5f * xx.x + thw[2 * qq];
  float h1 = 0.5f * xx.y + thw[2 * qq + 1];
  float c0 = cosf(h0), s0 = sinf(h0);
  float c1 = cosf(h1), s1 = sinf(h1);
  float cw[8], sw[8];
  cw[0] = dppf<QB0>(c0); cw[1] = dppf<QB0>(c1);
  sw[0] = dppf<QB0>(s0); sw[1] = dppf<QB0>(s1);
  cw[2] = dppf<QB1>(c0); cw[3] = dppf<QB1>(c1);
  sw[2] = dppf<QB1>(s0); sw[3] = dppf<QB1>(s1);
  cw[4] = dppf<QB2>(c0); cw[5] = dppf<QB2>(c1);
  sw[4] = dppf<QB2>(s0); sw[5] = dppf<QB2>(s1);
  cw[6] = dppf<QB3>(c0); cw[7] = dppf<QB3>(c1);
  sw[6] = dppf<QB3>(s0); sw[7] = dppf<QB3>(s1);

  // Product-state magnitudes over local bits 0..4 (scalar doubling),
  // then bit5 (wire 2, cw[2]/sw[2]) becomes the vector-half dimension.
  float mm[32];
  mm[0] = ((qq & 1) ? sw[1] : cw[1]) * ((qq & 2) ? sw[0] : cw[0]);
#pragma unroll
  for (int k = 0; k < 5; ++k) {
    const float cc = cw[7 - k], ss = sw[7 - k];
#pragma unroll
    for (int t = (1 << k) - 1; t >= 0; --t) {
      mm[t + (1 << k)] = mm[t] * ss;
      mm[t] = mm[t] * cc;
    }
  }

  // Phase (-i)^popcount(d): local part compile-time; half y has popc+1.
  f2 vr[32], vi[32];
  const int pq = __builtin_popcount(qq);
#pragma unroll
  for (int m = 0; m < 32; ++m) {
    const float mx = mm[m] * cw[2];
    const float my = mm[m] * sw[2];
    const int plx = __builtin_popcount(m) & 3;  // half y: plx+1 mod 4
    f2 r, i;
    if (plx == 0) { r.x = mx;    i.x = 0.0f;  r.y = 0.0f;  i.y = -my; }
    else if (plx == 1) { r.x = 0.0f; i.x = -mx; r.y = -my; i.y = 0.0f; }
    else if (plx == 2) { r.x = -mx; i.x = 0.0f; r.y = 0.0f; i.y = my; }
    else { r.x = 0.0f; i.x = mx;   r.y = my;   i.y = 0.0f; }
    vr[m] = r;
    vi[m] = i;
  }
  if (pq == 1) {
#pragma unroll
    for (int m = 0; m < 32; ++m) {
      f2 t = vr[m];
      vr[m] = vi[m];
      vi[m] = -t;
    }
  } else if (pq == 2) {
#pragma unroll
    for (int m = 0; m < 32; ++m) {
      vr[m] = -vr[m];
      vi[m] = -vi[m];
    }
  }

  // Layer-1 RX gates: FOLDED into the product state above (RX(a)RX(b)=RX(a+b)
  // on each wire; no CNOT between embedding and layer 1). Nothing to do.

  // Layer 2 RX (idx 8..15), masks B1*e_w = {C0,60,30,18,0C,06,03,C1}.
  gq0<QX3>(wc[8], wsn[8], vr, vi);      // 0xC0
  gq_l20<QX1>(wc[9], wsn[9], vr, vi);   // 0x60
  gl30(wc[10], wsn[10], vr, vi);        // 0x30
  gl<0x18>(wc[11], wsn[11], vr, vi);
  gl<0x0C>(wc[12], wsn[12], vr, vi);
  gl<0x06>(wc[13], wsn[13], vr, vi);
  gl<0x03>(wc[14], wsn[14], vr, vi);
  gq_l1<QX3>(wc[15], wsn[15], vr, vi);  // 0xC1

  // Readout (pruned WHT, validated round 4). Packed |amp|^2, 3-stage WHT
  // over bits0..2 per group g = m>>3 (bits3..4), signed g-accumulation,
  // then half-combine with u5 parity, then quad WHT over bits6..7.
  f2 wv[32];
#pragma unroll
  for (int m = 0; m < 32; ++m)
    wv[m] = F2FMA(vr[m], vr[m], vi[m] * vi[m]);
#pragma unroll
  for (int gi = 0; gi < 4; ++gi) {
#pragma unroll
    for (int k = 0; k < 3; ++k) {
#pragma unroll
      for (int j = 0; j < 8; ++j) {
        if (!(j & (1 << k))) {
          const int a = gi * 8 + j, b2 = a | (1 << k);
          f2 A = wv[a], B = wv[b2];
          wv[a] = A + B;
          wv[b2] = A - B;
        }
      }
    }
  }
  // g-sign sets: u2=1: [+,-,+,-]; u2=2: [+,+,-,-]; u2=3: [+,-,-,+].
  const f2 aA = (wv[5] + wv[13]) - (wv[21] + wv[29]);    // u2=2, ulo=5
  const f2 aBC = (wv[7] + wv[31]) - (wv[15] + wv[23]);   // u2=3, ulo=7
  const f2 aD = (wv[7] + wv[23]) - (wv[15] + wv[31]);    // u2=1, ulo=7
  const f2 aE = (wv[7] + wv[15]) - (wv[23] + wv[31]);    // u2=2, ulo=7
  const f2 aF = (wv[3] + wv[19]) - (wv[11] + wv[27]);    // u2=1, ulo=3
  const f2 aG = (wv[2] + wv[18]) - (wv[10] + wv[26]);    // u2=1, ulo=2
  const float accA = aA.x + aA.y;   // u5=0
  const float accB = aBC.x - aBC.y; // u5=1
  const float accC = aBC.x + aBC.y; // u5=0
  const float accD = aD.x - aD.y;   // u5=1
  const float accE = aE.x + aE.y;   // u5=0
  const float accF = aF.x - aF.y;   // u5=1
  const float accG = aG.x - aG.y;   // u5=1

  const float o15 = quad_wht(accA, qq);  // serves i0 (qq=3) and i6 (qq=1)
  const float o3F = quad_wht(accB, qq);
  const float o1F = quad_wht(accC, qq);
  const float o2F = quad_wht(accD, qq);
  const float o17 = quad_wht(accE, qq);
  const float o2B = quad_wht(accF, qq);
  const float o2A = quad_wht(accG, qq);

  float* orow = outp + (size_t)samp * 8;
  if (qq == 3) orow[0] = o15;
  if (qq == 2) {
    orow[1] = o3F;
    orow[3] = o2F;
    orow[5] = o2B;
    orow[7] = o2A;
  }
  if (qq == 1) {
    orow[2] = o1F;
    orow[4] = o17;
    orow[6] = o15;
  }
}

// Per-block weight trig into LDS (threads 0..31): cos/sin of all 16 weight
// half-angles plus raw half-angles of layer-1 weights (for the fold).
__device__ __forceinline__ void weight_trig(const float* __restrict__ w,
                                            float* __restrict__ tc,
                                            float* __restrict__ tsn,
                                            float* __restrict__ thw) {
  if (threadIdx.x < 32) {
    const int a = threadIdx.x & 15;
    const float half = 0.5f * w[a];
    if (threadIdx.x < 16) {
      tc[a] = cosf(half);
      if (a < 8) thw[a] = half;
    } else {
      tsn[a] = sinf(half);
    }
  }
  __syncthreads();
}

__global__ __launch_bounds__(256, 2) void mhaq_qproj3_kernel(
    const float* __restrict__ q, const float* __restrict__ k,
    const float* __restrict__ v, const float* __restrict__ wq,
    const float* __restrict__ wk, const float* __restrict__ wv,
    float* __restrict__ qp, float* __restrict__ kp, float* __restrict__ vp) {
  __shared__ float tc[16], tsn[16], thw[8];
  const int wg = blockIdx.x * 4 + (threadIdx.x >> 6);  // 0..6143
  const int proj = wg >> 11;  // 2048 waves per projection; block-uniform
  const float* wsel = proj == 0 ? wq : proj == 1 ? wk : wv;
  weight_trig(wsel, tc, tsn, thw);
  const float* in = proj == 0 ? q : proj == 1 ? k : v;
  float* op = proj == 0 ? qp : proj == 1 ? kp : vp;
  qsim_wave(in, op, (wg & 2047) * 16, tc, tsn, thw);
}

__global__ __launch_bounds__(256, 2) void mhaq_qproj1_kernel(
    const float* __restrict__ ctx, const float* __restrict__ wd,
    float* __restrict__ outp) {
  __shared__ float tc[16], tsn[16], thw[8];
  weight_trig(wd, tc, tsn, thw);
  const int wg = blockIdx.x * 4 + (threadIdx.x >> 6);  // 0..2047
  qsim_wave(ctx, outp, wg * 16, tc, tsn, thw);
}

// Full-wave reductions: quad DPP + row mirrors + 2 shfl stages (only DS use).
__device__ __forceinline__ float wred_sum(float v) {
  v += dppf<QX1>(v);
  v += dppf<QX2>(v);
  v += dppf<ROW_HALF_MIRROR>(v);  // xor7 == xor4 after quad-uniform
  v += dppf<ROW_MIRROR>(v);       // xor15 == xor8 after 8-uniform
  v += __shfl_xor(v, 16, 64);
  v += __shfl_xor(v, 32, 64);
  return v;
}
__device__ __forceinline__ float wred_max(float v) {
  v = fmaxf(v, dppf<QX1>(v));
  v = fmaxf(v, dppf<QX2>(v));
  v = fmaxf(v, dppf<ROW_HALF_MIRROR>(v));
  v = fmaxf(v, dppf<ROW_MIRROR>(v));
  v = fmaxf(v, __shfl_xor(v, 16, 64));
  v = fmaxf(v, __shfl_xor(v, 32, 64));
  return v;
}

// Attention: one wave per (b,h, 8-row chunk); K/V head slice in VGPRs.
// Lane owns j = t*256 + lane*4 + c (t,c in 0..3) so the attn-row store for
// each t is one dense, aligned 1 KB block per wave instruction (full-line
// HBM writes). Reductions/PV are ownership-agnostic.
__global__ __launch_bounds__(256, 2) void mhaq_attn_kernel(
    const float* __restrict__ qp, const float* __restrict__ kp,
    const float* __restrict__ vp, float* __restrict__ ctx,
    float* __restrict__ attn) {
  const int wg = blockIdx.x * 4 + (threadIdx.x >> 6);  // 0..8191
  const int bh = wg >> 7;      // 64 (b,h) pairs, 128 chunks each
  const int chunk = wg & 127;  // 8 rows per chunk
  const int b = bh >> 1, h = bh & 1;
  const int lane = threadIdx.x & 63;

  float4 kreg[16], vreg[16];
  const float* kbase = kp + (size_t)b * 1024 * 8 + h * 4;
  const float* vbase = vp + (size_t)b * 1024 * 8 + h * 4;
#pragma unroll
  for (int t = 0; t < 4; ++t) {
#pragma unroll
    for (int c = 0; c < 4; ++c) {
      const size_t j = (size_t)t * 256 + lane * 4 + c;
      kreg[t * 4 + c] = *(const float4*)(kbase + j * 8);
      vreg[t * 4 + c] = *(const float4*)(vbase + j * 8);
    }
  }

  for (int r = 0; r < 8; ++r) {
    const int i = chunk * 8 + r;
    const float4 qv = *(const float4*)(qp + ((size_t)b * 1024 + i) * 8 + h * 4);
    float e[16];
    float mx = -1e30f;
#pragma unroll
    for (int t = 0; t < 16; ++t) {
      float s = qv.x * kreg[t].x + qv.y * kreg[t].y + qv.z * kreg[t].z +
                qv.w * kreg[t].w;
      s *= 0.5f;  // 1/sqrt(D), D=4
      e[t] = s;
      mx = fmaxf(mx, s);
    }
    mx = wred_max(mx);
    float sum = 0.0f;
#pragma unroll
    for (int t = 0; t < 16; ++t) {
      e[t] = __expf(e[t] - mx);
      sum += e[t];
    }
    sum = wred_sum(sum);
    const float rinv = 1.0f / sum;

    float a0 = 0.f, a1 = 0.f, a2 = 0.f, a3 = 0.f;
    float* arow = attn + ((size_t)(bh * 1024 + i)) * 1024;
#pragma unroll
    for (int t = 0; t < 4; ++t) {
      float p0 = e[4 * t] * rinv, p1 = e[4 * t + 1] * rinv,
            p2 = e[4 * t + 2] * rinv, p3 = e[4 * t + 3] * rinv;
      // Dense store: 64 lanes x float4 = contiguous 1 KB at arow + t*1024B.
      *(float4*)(arow + t * 256 + lane * 4) = make_float4(p0, p1, p2, p3);
      a0 = fmaf(p0, vreg[4 * t].x, a0);
      a1 = fmaf(p0, vreg[4 * t].y, a1);
      a2 = fmaf(p0, vreg[4 * t].z, a2);
      a3 = fmaf(p0, vreg[4 * t].w, a3);
      a0 = fmaf(p1, vreg[4 * t + 1].x, a0);
      a1 = fmaf(p1, vreg[4 * t + 1].y, a1);
      a2 = fmaf(p1, vreg[4 * t + 1].z, a2);
      a3 = fmaf(p1, vreg[4 * t + 1].w, a3);
      a0 = fmaf(p2, vreg[4 * t + 2].x, a0);
      a1 = fmaf(p2, vreg[4 * t + 2].y, a1);
      a2 = fmaf(p2, vreg[4 * t + 2].z, a2);
      a3 = fmaf(p2, vreg[4 * t + 2].w, a3);
      a0 = fmaf(p3, vreg[4 * t + 3].x, a0);
      a1 = fmaf(p3, vreg[4 * t + 3].y, a1);
      a2 = fmaf(p3, vreg[4 * t + 3].z, a2);
      a3 = fmaf(p3, vreg[4 * t + 3].w, a3);
    }
    a0 = wred_sum(a0);
    a1 = wred_sum(a1);
    a2 = wred_sum(a2);
    a3 = wred_sum(a3);
    if (lane == 0)
      *(float4*)(ctx + ((size_t)b * 1024 + i) * 8 + h * 4) =
          make_float4(a0, a1, a2, a3);
  }
}

extern "C" void kernel_launch(void* const* d_in, const int* in_sizes, int n_in,
                              void* d_out, int out_size, void* d_ws,
                              size_t ws_size, hipStream_t stream) {
  (void)in_sizes; (void)n_in; (void)out_size; (void)ws_size;
  const float* q = (const float*)d_in[0];
  const float* k = (const float*)d_in[1];
  const float* v = (const float*)d_in[2];
  const float* wq = (const float*)d_in[3];
  const float* wk = (const float*)d_in[4];
  const float* wv = (const float*)d_in[5];
  const float* wd = (const float*)d_in[6];
  float* outp = (float*)d_out;  // [0, 262144): out; then attn (B,H,S,S)
  float* attn = outp + 262144;

  float* wsf = (float*)d_ws;
  float* qp = wsf;
  float* kp = qp + (size_t)NSAMP * 8;
  float* vp = kp + (size_t)NSAMP * 8;
  float* ctx = vp + (size_t)NSAMP * 8;  // concat layout [b,s,h*4+d]

  hipLaunchKernelGGL(mhaq_qproj3_kernel, dim3(1536), dim3(256), 0, stream, q,
                     k, v, wq, wk, wv, qp, kp, vp);
  hipLaunchKernelGGL(mhaq_attn_kernel, dim3(2048), dim3(256), 0, stream, qp,
                     kp, vp, ctx, attn);
  hipLaunchKernelGGL(mhaq_qproj1_kernel, dim3(512), dim3(256), 0, stream, ctx,
                     wd, outp);
}

// Round 8
// 337.029 us; speedup vs baseline: 1.2122x; 1.0080x over previous
//
#include <hip/hip_runtime.h>
#include <math.h>

// ----------------------------------------------------------------------------
// MultiHeadAttentionQuantum: 8-qubit RX/CNOT-ring circuit projections + MHA.
//
// Timing model (validated rounds 2-7): dur_us = harness fill (~167us, fixed)
//   + qproj3 (~71) + attn (~78) + qproj1 (~24).
//
// Round-10 (this round): attn write-path. 268MB in 78us = 3.44 TB/s, but the
//   harness fill kernel writes at 6.4 TB/s on this chip -> our write-back
//   stores (L2-allocating, dirty-eviction drain) are the suspect. Changes:
//   (a) NON-TEMPORAL stores for the dense 1KB-per-instruction attn stream
//       (round-2's nt disaster was nt+SPARSE 64B-strided stores; since
//       round 3 the stores are full-line dense = the fill pattern);
//   (b) drop softmax max-subtraction: scores exactly bounded |s|<=2
//       (q,k in [-1,1]^4, scale 0.5), exp in [0.135,7.39], sum<7600 --
//       mathematically identical softmax, removes a 6-stage DPP chain +
//       16-deep max chain from each row's serial path.
//
// qsim (rounds 5+9, verified): packed f2 amps along local bit5; layer-1 RX
//   folded into product state (RX(x)RX(th0)=RX(x+th0), no CNOT between);
//   L2 masks {C0,60,30,18,0C,06,03,C1}; pruned-WHT readout.
//
// attn (round 3): lane owns j = t*256 + lane*4 + c; each attn-row store is
//   one dense aligned 1KB block per wave instruction; 8 rows/wave, grid 2048.
// ----------------------------------------------------------------------------

#define NSAMP 32768  // B*S = 32*1024

typedef float f2 __attribute__((ext_vector_type(2)));
typedef float f4 __attribute__((ext_vector_type(4)));

// DPP ctrl codes (gfx9/CDNA): quad_perm xor1/2/3, quad bcast j, row mirrors.
#define QX1 0xB1  // [1,0,3,2]
#define QX2 0x4E  // [2,3,0,1]
#define QX3 0x1B  // [3,2,1,0]
#define QB0 0x00
#define QB1 0x55
#define QB2 0xAA
#define QB3 0xFF
#define ROW_MIRROR 0x140       // lane ^ 15 within 16
#define ROW_HALF_MIRROR 0x141  // lane ^ 7 within 8

template <int CTRL>
__device__ __forceinline__ float dppf(float x) {
  int xi = __float_as_int(x);
  return __int_as_float(
      __builtin_amdgcn_update_dpp(xi, xi, CTRL, 0xF, 0xF, false));
}

template <int CTRL>
__device__ __forceinline__ f2 dpp2(f2 v) {
  f2 r;
  r.x = dppf<CTRL>(v.x);
  r.y = dppf<CTRL>(v.y);
  return r;
}

__device__ __forceinline__ f2 swap2(f2 v) {
  f2 r;
  r.x = v.y;
  r.y = v.x;
  return r;
}

#define F2FMA(a, b, c) __builtin_elementwise_fma((a), (b), (c))

// ---- packed gates: vr/vi are 32 x f2; halves = local bit5 (0 / 1) ----------

// Cross-lane RX, no local mask (0xC0).
template <int CTRL>
__device__ __forceinline__ void gq0(float c, float s, f2* vr, f2* vi) {
  const f2 c2 = {c, c}, s2 = {s, s};
#pragma unroll
  for (int m = 0; m < 32; ++m) {
    f2 pr = dpp2<CTRL>(vr[m]);
    f2 pi = dpp2<CTRL>(vi[m]);
    vr[m] = F2FMA(c2, vr[m], s2 * pi);
    vi[m] = F2FMA(c2, vi[m], -s2 * pr);
  }
}

// Cross-lane RX + local bit0 (0xC1).
template <int CTRL>
__device__ __forceinline__ void gq_l1(float c, float s, f2* vr, f2* vi) {
  const f2 c2 = {c, c}, s2 = {s, s};
#pragma unroll
  for (int m = 0; m < 32; m += 2) {
    f2 pr0 = dpp2<CTRL>(vr[m]), pi0 = dpp2<CTRL>(vi[m]);
    f2 pr1 = dpp2<CTRL>(vr[m + 1]), pi1 = dpp2<CTRL>(vi[m + 1]);
    vr[m] = F2FMA(c2, vr[m], s2 * pi1);
    vi[m] = F2FMA(c2, vi[m], -s2 * pr1);
    vr[m + 1] = F2FMA(c2, vr[m + 1], s2 * pi0);
    vi[m + 1] = F2FMA(c2, vi[m + 1], -s2 * pr0);
  }
}

// Cross-lane RX + local bit5 (0x60): partner is DPP of the other half.
template <int CTRL>
__device__ __forceinline__ void gq_l20(float c, float s, f2* vr, f2* vi) {
  const f2 c2 = {c, c}, s2 = {s, s};
#pragma unroll
  for (int m = 0; m < 32; ++m) {
    f2 pr = dpp2<CTRL>(vr[m]);
    f2 pi = dpp2<CTRL>(vi[m]);
    vr[m] = F2FMA(c2, vr[m], s2 * swap2(pi));
    vi[m] = F2FMA(c2, vi[m], -s2 * swap2(pr));
  }
}

// Intra-lane RX, mask within bits0..4 (both halves identical pattern).
template <int ML>
__device__ __forceinline__ void gl(float c, float s, f2* vr, f2* vi) {
  constexpr int HB = ML >= 16 ? 16 : ML >= 8 ? 8 : ML >= 4 ? 4
                     : ML >= 2 ? 2 : 1;
  const f2 c2 = {c, c}, s2 = {s, s};
#pragma unroll
  for (int m = 0; m < 32; ++m) {
    if (!(m & HB)) {
      const int p = m ^ ML;
      f2 a0r = vr[m], a0i = vi[m], a1r = vr[p], a1i = vi[p];
      vr[m] = F2FMA(c2, a0r, s2 * a1i);
      vi[m] = F2FMA(c2, a0i, -s2 * a1r);
      vr[p] = F2FMA(c2, a1r, s2 * a0i);
      vi[p] = F2FMA(c2, a1i, -s2 * a0r);
    }
  }
}

// Intra-lane RX, mask = bits4+5 (0x30): partner = other half of m^0x10.
__device__ __forceinline__ void gl30(float c, float s, f2* vr, f2* vi) {
  const f2 c2 = {c, c}, s2 = {s, s};
#pragma unroll
  for (int m = 0; m < 32; ++m) {
    if (!(m & 0x10)) {
      const int p = m ^ 0x10;
      f2 or0 = vr[m], oi0 = vi[m], or1 = vr[p], oi1 = vi[p];
      vr[m] = F2FMA(c2, or0, s2 * swap2(oi1));
      vi[m] = F2FMA(c2, oi0, -s2 * swap2(or1));
      vr[p] = F2FMA(c2, or1, s2 * swap2(oi0));
      vi[p] = F2FMA(c2, oi1, -s2 * swap2(or0));
    }
  }
}

// 2-stage signed quad WHT: returns, in quad-lane u, sum_q (-1)^<u,q> W_q.
__device__ __forceinline__ float quad_wht(float v, int qq) {
  float u = dppf<QX1>(v);
  v = (qq & 1) ? (u - v) : (v + u);
  u = dppf<QX2>(v);
  v = (qq & 2) ? (u - v) : (v + u);
  return v;
}

// in:  sample angle rows [samp][8]; wc/wsn: cos/sin of the layer-2 weight
// half-angles (LDS, idx 8..15); thw: 0.5*theta0_w (layer-1 fold, idx 0..7);
// out: [samp][8] expvals. Wave handles samples [sampBase, sampBase+16).
__device__ __forceinline__ void qsim_wave(const float* __restrict__ in,
                                          float* __restrict__ outp,
                                          int sampBase,
                                          const float* __restrict__ wc,
                                          const float* __restrict__ wsn,
                                          const float* __restrict__ thw) {
  const int lane = threadIdx.x & 63;
  const int qq = lane & 3;
  const int g = lane >> 2;
  const int samp = sampBase + g;

  // Input trig with layer-1 RX folded in: RX(x)RX(th0) = RX(x+th0), so the
  // product state uses half-angle 0.5*x_w + 0.5*th0_w. Lane qq computes
  // wires 2qq, 2qq+1; quad-broadcast all 8.
  const float2 xx = *(const float2*)(in + (size_t)samp * 8 + 2 * qq);
  float h0 = 0.5f * xx.x + thw[2 * qq];
  float h1 = 0.5f * xx.y + thw[2 * qq + 1];
  float c0 = cosf(h0), s0 = sinf(h0);
  float c1 = cosf(h1), s1 = sinf(h1);
  float cw[8], sw[8];
  cw[0] = dppf<QB0>(c0); cw[1] = dppf<QB0>(c1);
  sw[0] = dppf<QB0>(s0); sw[1] = dppf<QB0>(s1);
  cw[2] = dppf<QB1>(c0); cw[3] = dppf<QB1>(c1);
  sw[2] = dppf<QB1>(s0); sw[3] = dppf<QB1>(s1);
  cw[4] = dppf<QB2>(c0); cw[5] = dppf<QB2>(c1);
  sw[4] = dppf<QB2>(s0); sw[5] = dppf<QB2>(s1);
  cw[6] = dppf<QB3>(c0); cw[7] = dppf<QB3>(c1);
  sw[6] = dppf<QB3>(s0); sw[7] = dppf<QB3>(s1);

  // Product-state magnitudes over local bits 0..4 (scalar doubling),
  // then bit5 (wire 2, cw[2]/sw[2]) becomes the vector-half dimension.
  float mm[32];
  mm[0] = ((qq & 1) ? sw[1] : cw[1]) * ((qq & 2) ? sw[0] : cw[0]);
#pragma unroll
  for (int k = 0; k < 5; ++k) {
    const float cc = cw[7 - k], ss = sw[7 - k];
#pragma unroll
    for (int t = (1 << k) - 1; t >= 0; --t) {
      mm[t + (1 << k)] = mm[t] * ss;
      mm[t] = mm[t] * cc;
    }
  }

  // Phase (-i)^popcount(d): local part compile-time; half y has popc+1.
  f2 vr[32], vi[32];
  const int pq = __builtin_popcount(qq);
#pragma unroll
  for (int m = 0; m < 32; ++m) {
    const float mx = mm[m] * cw[2];
    const float my = mm[m] * sw[2];
    const int plx = __builtin_popcount(m) & 3;  // half y: plx+1 mod 4
    f2 r, i;
    if (plx == 0) { r.x = mx;    i.x = 0.0f;  r.y = 0.0f;  i.y = -my; }
    else if (plx == 1) { r.x = 0.0f; i.x = -mx; r.y = -my; i.y = 0.0f; }
    else if (plx == 2) { r.x = -mx; i.x = 0.0f; r.y = 0.0f; i.y = my; }
    else { r.x = 0.0f; i.x = mx;   r.y = my;   i.y = 0.0f; }
    vr[m] = r;
    vi[m] = i;
  }
  if (pq == 1) {
#pragma unroll
    for (int m = 0; m < 32; ++m) {
      f2 t = vr[m];
      vr[m] = vi[m];
      vi[m] = -t;
    }
  } else if (pq == 2) {
#pragma unroll
    for (int m = 0; m < 32; ++m) {
      vr[m] = -vr[m];
      vi[m] = -vi[m];
    }
  }

  // Layer-1 RX gates: FOLDED into the product state above.

  // Layer 2 RX (idx 8..15), masks B1*e_w = {C0,60,30,18,0C,06,03,C1}.
  gq0<QX3>(wc[8], wsn[8], vr, vi);      // 0xC0
  gq_l20<QX1>(wc[9], wsn[9], vr, vi);   // 0x60
  gl30(wc[10], wsn[10], vr, vi);        // 0x30
  gl<0x18>(wc[11], wsn[11], vr, vi);
  gl<0x0C>(wc[12], wsn[12], vr, vi);
  gl<0x06>(wc[13], wsn[13], vr, vi);
  gl<0x03>(wc[14], wsn[14], vr, vi);
  gq_l1<QX3>(wc[15], wsn[15], vr, vi);  // 0xC1

  // Readout (pruned WHT, validated round 4). Packed |amp|^2, 3-stage WHT
  // over bits0..2 per group g = m>>3 (bits3..4), signed g-accumulation,
  // then half-combine with u5 parity, then quad WHT over bits6..7.
  f2 wv[32];
#pragma unroll
  for (int m = 0; m < 32; ++m)
    wv[m] = F2FMA(vr[m], vr[m], vi[m] * vi[m]);
#pragma unroll
  for (int gi = 0; gi < 4; ++gi) {
#pragma unroll
    for (int k = 0; k < 3; ++k) {
#pragma unroll
      for (int j = 0; j < 8; ++j) {
        if (!(j & (1 << k))) {
          const int a = gi * 8 + j, b2 = a | (1 << k);
          f2 A = wv[a], B = wv[b2];
          wv[a] = A + B;
          wv[b2] = A - B;
        }
      }
    }
  }
  // g-sign sets: u2=1: [+,-,+,-]; u2=2: [+,+,-,-]; u2=3: [+,-,-,+].
  const f2 aA = (wv[5] + wv[13]) - (wv[21] + wv[29]);    // u2=2, ulo=5
  const f2 aBC = (wv[7] + wv[31]) - (wv[15] + wv[23]);   // u2=3, ulo=7
  const f2 aD = (wv[7] + wv[23]) - (wv[15] + wv[31]);    // u2=1, ulo=7
  const f2 aE = (wv[7] + wv[15]) - (wv[23] + wv[31]);    // u2=2, ulo=7
  const f2 aF = (wv[3] + wv[19]) - (wv[11] + wv[27]);    // u2=1, ulo=3
  const f2 aG = (wv[2] + wv[18]) - (wv[10] + wv[26]);    // u2=1, ulo=2
  const float accA = aA.x + aA.y;   // u5=0
  const float accB = aBC.x - aBC.y; // u5=1
  const float accC = aBC.x + aBC.y; // u5=0
  const float accD = aD.x - aD.y;   // u5=1
  const float accE = aE.x + aE.y;   // u5=0
  const float accF = aF.x - aF.y;   // u5=1
  const float accG = aG.x - aG.y;   // u5=1

  const float o15 = quad_wht(accA, qq);  // serves i0 (qq=3) and i6 (qq=1)
  const float o3F = quad_wht(accB, qq);
  const float o1F = quad_wht(accC, qq);
  const float o2F = quad_wht(accD, qq);
  const float o17 = quad_wht(accE, qq);
  const float o2B = quad_wht(accF, qq);
  const float o2A = quad_wht(accG, qq);

  float* orow = outp + (size_t)samp * 8;
  if (qq == 3) orow[0] = o15;
  if (qq == 2) {
    orow[1] = o3F;
    orow[3] = o2F;
    orow[5] = o2B;
    orow[7] = o2A;
  }
  if (qq == 1) {
    orow[2] = o1F;
    orow[4] = o17;
    orow[6] = o15;
  }
}

// Per-block weight trig into LDS (threads 0..31): cos/sin of all 16 weight
// half-angles plus raw half-angles of layer-1 weights (for the fold).
__device__ __forceinline__ void weight_trig(const float* __restrict__ w,
                                            float* __restrict__ tc,
                                            float* __restrict__ tsn,
                                            float* __restrict__ thw) {
  if (threadIdx.x < 32) {
    const int a = threadIdx.x & 15;
    const float half = 0.5f * w[a];
    if (threadIdx.x < 16) {
      tc[a] = cosf(half);
      if (a < 8) thw[a] = half;
    } else {
      tsn[a] = sinf(half);
    }
  }
  __syncthreads();
}

__global__ __launch_bounds__(256, 2) void mhaq_qproj3_kernel(
    const float* __restrict__ q, const float* __restrict__ k,
    const float* __restrict__ v, const float* __restrict__ wq,
    const float* __restrict__ wk, const float* __restrict__ wv,
    float* __restrict__ qp, float* __restrict__ kp, float* __restrict__ vp) {
  __shared__ float tc[16], tsn[16], thw[8];
  const int wg = blockIdx.x * 4 + (threadIdx.x >> 6);  // 0..6143
  const int proj = wg >> 11;  // 2048 waves per projection; block-uniform
  const float* wsel = proj == 0 ? wq : proj == 1 ? wk : wv;
  weight_trig(wsel, tc, tsn, thw);
  const float* in = proj == 0 ? q : proj == 1 ? k : v;
  float* op = proj == 0 ? qp : proj == 1 ? kp : vp;
  qsim_wave(in, op, (wg & 2047) * 16, tc, tsn, thw);
}

__global__ __launch_bounds__(256, 2) void mhaq_qproj1_kernel(
    const float* __restrict__ ctx, const float* __restrict__ wd,
    float* __restrict__ outp) {
  __shared__ float tc[16], tsn[16], thw[8];
  weight_trig(wd, tc, tsn, thw);
  const int wg = blockIdx.x * 4 + (threadIdx.x >> 6);  // 0..2047
  qsim_wave(ctx, outp, wg * 16, tc, tsn, thw);
}

// Full-wave reductions: quad DPP + row mirrors + 2 shfl stages (only DS use).
__device__ __forceinline__ float wred_sum(float v) {
  v += dppf<QX1>(v);
  v += dppf<QX2>(v);
  v += dppf<ROW_HALF_MIRROR>(v);  // xor7 == xor4 after quad-uniform
  v += dppf<ROW_MIRROR>(v);       // xor15 == xor8 after 8-uniform
  v += __shfl_xor(v, 16, 64);
  v += __shfl_xor(v, 32, 64);
  return v;
}

// Attention: one wave per (b,h, 8-row chunk); K/V head slice in VGPRs.
// Lane owns j = t*256 + lane*4 + c (t,c in 0..3) so the attn-row store for
// each t is one dense, aligned 1 KB block per wave instruction (full-line
// HBM writes, nontemporal: stream past L2). Softmax WITHOUT max-shift:
// scores exactly bounded |s| <= 2 (q,k in [-1,1]^4 expvals, scale 0.5), so
// exp in [0.135, 7.39] and row-sum < 7600 -- identical softmax in fp32.
__global__ __launch_bounds__(256, 2) void mhaq_attn_kernel(
    const float* __restrict__ qp, const float* __restrict__ kp,
    const float* __restrict__ vp, float* __restrict__ ctx,
    float* __restrict__ attn) {
  const int wg = blockIdx.x * 4 + (threadIdx.x >> 6);  // 0..8191
  const int bh = wg >> 7;      // 64 (b,h) pairs, 128 chunks each
  const int chunk = wg & 127;  // 8 rows per chunk
  const int b = bh >> 1, h = bh & 1;
  const int lane = threadIdx.x & 63;

  float4 kreg[16], vreg[16];
  const float* kbase = kp + (size_t)b * 1024 * 8 + h * 4;
  const float* vbase = vp + (size_t)b * 1024 * 8 + h * 4;
#pragma unroll
  for (int t = 0; t < 4; ++t) {
#pragma unroll
    for (int c = 0; c < 4; ++c) {
      const size_t j = (size_t)t * 256 + lane * 4 + c;
      kreg[t * 4 + c] = *(const float4*)(kbase + j * 8);
      vreg[t * 4 + c] = *(const float4*)(vbase + j * 8);
    }
  }

  for (int r = 0; r < 8; ++r) {
    const int i = chunk * 8 + r;
    const float4 qv = *(const float4*)(qp + ((size_t)b * 1024 + i) * 8 + h * 4);
    float e[16];
    float sum = 0.0f;
#pragma unroll
    for (int t = 0; t < 16; ++t) {
      float s = qv.x * kreg[t].x + qv.y * kreg[t].y + qv.z * kreg[t].z +
                qv.w * kreg[t].w;
      e[t] = __expf(s * 0.5f);  // 1/sqrt(D), D=4; no max-shift needed
      sum += e[t];
    }
    sum = wred_sum(sum);
    const float rinv = 1.0f / sum;

    float a0 = 0.f, a1 = 0.f, a2 = 0.f, a3 = 0.f;
    float* arow = attn + ((size_t)(bh * 1024 + i)) * 1024;
#pragma unroll
    for (int t = 0; t < 4; ++t) {
      float p0 = e[4 * t] * rinv, p1 = e[4 * t + 1] * rinv,
            p2 = e[4 * t + 2] * rinv, p3 = e[4 * t + 3] * rinv;
      // Dense nontemporal store: 64 lanes x float4 = contiguous 1 KB block.
      f4 pv = {p0, p1, p2, p3};
      __builtin_nontemporal_store(pv, (f4*)(arow + t * 256 + lane * 4));
      a0 = fmaf(p0, vreg[4 * t].x, a0);
      a1 = fmaf(p0, vreg[4 * t].y, a1);
      a2 = fmaf(p0, vreg[4 * t].z, a2);
      a3 = fmaf(p0, vreg[4 * t].w, a3);
      a0 = fmaf(p1, vreg[4 * t + 1].x, a0);
      a1 = fmaf(p1, vreg[4 * t + 1].y, a1);
      a2 = fmaf(p1, vreg[4 * t + 1].z, a2);
      a3 = fmaf(p1, vreg[4 * t + 1].w, a3);
      a0 = fmaf(p2, vreg[4 * t + 2].x, a0);
      a1 = fmaf(p2, vreg[4 * t + 2].y, a1);
      a2 = fmaf(p2, vreg[4 * t + 2].z, a2);
      a3 = fmaf(p2, vreg[4 * t + 2].w, a3);
      a0 = fmaf(p3, vreg[4 * t + 3].x, a0);
      a1 = fmaf(p3, vreg[4 * t + 3].y, a1);
      a2 = fmaf(p3, vreg[4 * t + 3].z, a2);
      a3 = fmaf(p3, vreg[4 * t + 3].w, a3);
    }
    a0 = wred_sum(a0);
    a1 = wred_sum(a1);
    a2 = wred_sum(a2);
    a3 = wred_sum(a3);
    if (lane == 0)
      *(float4*)(ctx + ((size_t)b * 1024 + i) * 8 + h * 4) =
          make_float4(a0, a1, a2, a3);
  }
}

extern "C" void kernel_launch(void* const* d_in, const int* in_sizes, int n_in,
                              void* d_out, int out_size, void* d_ws,
                              size_t ws_size, hipStream_t stream) {
  (void)in_sizes; (void)n_in; (void)out_size; (void)ws_size;
  const float* q = (const float*)d_in[0];
  const float* k = (const float*)d_in[1];
  const float* v = (const float*)d_in[2];
  const float* wq = (const float*)d_in[3];
  const float* wk = (const float*)d_in[4];
  const float* wv = (const float*)d_in[5];
  const float* wd = (const float*)d_in[6];
  float* outp = (float*)d_out;  // [0, 262144): out; then attn (B,H,S,S)
  float* attn = outp + 262144;

  float* wsf = (float*)d_ws;
  float* qp = wsf;
  float* kp = qp + (size_t)NSAMP * 8;
  float* vp = kp + (size_t)NSAMP * 8;
  float* ctx = vp + (size_t)NSAMP * 8;  // concat layout [b,s,h*4+d]

  hipLaunchKernelGGL(mhaq_qproj3_kernel, dim3(1536), dim3(256), 0, stream, q,
                     k, v, wq, wk, wv, qp, kp, vp);
  hipLaunchKernelGGL(mhaq_attn_kernel, dim3(2048), dim3(256), 0, stream, qp,
                     kp, vp, ctx, attn);
  hipLaunchKernelGGL(mhaq_qproj1_kernel, dim3(512), dim3(256), 0, stream, ctx,
                     wd, outp);
}